// Round 1
// baseline (20159.062 us; speedup 1.0000x reference)
//
#include <hip/hip_runtime.h>
#include <hip/hip_bf16.h>
#include <stdint.h>

#define CDIV(a,b) (((a)+(b)-1)/(b))

// ---------------- preprocessing kernels ----------------

__global__ void k_flag0(int* flag){ *flag = 0; }

// Detect int32 vs int64 edge_index: view buffer as int32; for int64 data the
// odd positions (high words, values < 2^31) are all zero. For int32 data they
// are random node ids (nonzero w.h.p.). Benign race: all writers store 1.
__global__ void k_detect(const int* __restrict__ ei, int E, int* __restrict__ flag){
  int t = blockIdx.x*blockDim.x + threadIdx.x;
  if(t < 4096 && t < E){
    if(ei[2*t+1] != 0) *flag = 1;
  }
}

// e32[0..E) = src, e32[E..2E) = dst
__global__ void k_convert(const int* __restrict__ ei, int E2, const int* __restrict__ flag,
                          int* __restrict__ out){
  int e = blockIdx.x*blockDim.x + threadIdx.x;
  if(e < E2){
    out[e] = (*flag) ? ei[e] : ei[2*e];   // int64: take low word
  }
}

__global__ void k_counts1(int* __restrict__ counts, int N){
  int i = blockIdx.x*blockDim.x+threadIdx.x;
  if(i<N) counts[i]=1;   // self-loop
}

__global__ void k_count(const int* __restrict__ dst, int E, int* __restrict__ counts){
  int e = blockIdx.x*blockDim.x+threadIdx.x;
  if(e<E) atomicAdd(&counts[dst[e]], 1);
}

__global__ void k_dis(const int* __restrict__ counts, float* __restrict__ dis, int N){
  int i=blockIdx.x*blockDim.x+threadIdx.x;
  if(i<N) dis[i] = rsqrtf((float)counts[i]);
}

// ---- 3-pass exclusive scan (1024 elems / block) ----
__global__ void k_scan1(const int* __restrict__ counts, int N, int* __restrict__ bsums){
  __shared__ int lds[256];
  const int t=threadIdx.x, b=blockIdx.x;
  int basei = b*1024 + t*4;
  int s=0;
  #pragma unroll
  for(int j=0;j<4;j++){ int i=basei+j; if(i<N) s+=counts[i]; }
  lds[t]=s; __syncthreads();
  for(int o=128;o>0;o>>=1){ if(t<o) lds[t]+=lds[t+o]; __syncthreads(); }
  if(t==0) bsums[b]=lds[0];
}

__global__ void k_scan2(const int* __restrict__ bsums, int NB, int* __restrict__ boffs,
                        int* __restrict__ row_ptr, int N){
  int acc=0;
  for(int b=0;b<NB;b++){ boffs[b]=acc; acc+=bsums[b]; }
  row_ptr[N]=acc;
}

__global__ void k_scan3(const int* __restrict__ counts, int N, const int* __restrict__ boffs,
                        int* __restrict__ row_ptr, int* __restrict__ cursor){
  __shared__ int lds[256];
  const int t=threadIdx.x, b=blockIdx.x;
  int basei = b*1024 + t*4;
  int v[4]; int s=0;
  #pragma unroll
  for(int j=0;j<4;j++){ int i=basei+j; v[j]=(i<N)?counts[i]:0; s+=v[j]; }
  lds[t]=s; __syncthreads();
  for(int o=1;o<256;o<<=1){
    int yv = (t>=o)? lds[t-o] : 0;
    __syncthreads();
    lds[t] += yv;
    __syncthreads();
  }
  int run = boffs[b] + lds[t] - s;   // exclusive prefix for this thread
  #pragma unroll
  for(int j=0;j<4;j++){
    int i=basei+j;
    if(i<N){ row_ptr[i]=run; cursor[i]=run; run+=v[j]; }
  }
}

// CSR fill: (src, norm) pairs grouped by dst. Self-loops appended as edges E..E+N.
__global__ void k_fill(const int* __restrict__ src, const int* __restrict__ dst, int E, int N,
                       const float* __restrict__ dis, int* __restrict__ cursor,
                       int2* __restrict__ pack){
  int e = blockIdx.x*blockDim.x+threadIdx.x;
  if(e < E){
    int s=src[e], d=dst[e];
    int pos=atomicAdd(&cursor[d],1);
    pack[pos]=make_int2(s, __float_as_int(dis[s]*dis[d]));
  } else if(e < E+N){
    int i=e-E;
    int pos=atomicAdd(&cursor[i],1);
    float di=dis[i];
    pack[pos]=make_int2(i, __float_as_int(di*di));
  }
}

// Precompute time-invariant aggregates: aggones[d]=sum norm, aggx[d]=sum norm*x[src]
__global__ void k_aggx(const int* __restrict__ row_ptr, const int2* __restrict__ pack,
                       const float* __restrict__ x, float* __restrict__ aggx,
                       float* __restrict__ aggones, int N){
  int n = blockIdx.x*blockDim.x+threadIdx.x;
  if(n>=N) return;
  float sa=0.f, sx=0.f;
  int e1 = row_ptr[n+1];
  for(int e=row_ptr[n]; e<e1; e++){
    int2 p = pack[e];
    float nrm = __int_as_float(p.y);
    sa += nrm;
    sx = fmaf(nrm, x[p.x], sx);
  }
  aggones[n]=sa; aggx[n]=sx;
}

// h = relu(relu(y0 @ fc1W + fc1b) @ fc2W + fc2b), stored stride-32 (26 used).
// Also copies y0 to output row 0.
__global__ void k_init(const float* __restrict__ y0, float* __restrict__ out0,
                       const float* __restrict__ fc1W, const float* __restrict__ fc1b,
                       const float* __restrict__ fc2W, const float* __restrict__ fc2b,
                       float* __restrict__ h, int N){
  int n = blockIdx.x*blockDim.x+threadIdx.x;
  if(n>=N) return;
  float v = y0[n];
  out0[n] = v;
  float h0[32];
  #pragma unroll
  for(int j=0;j<32;j++) h0[j] = fmaxf(fmaf(v, fc1W[j], fc1b[j]), 0.f);
  for(int k=0;k<26;k++){
    float s = fc2b[k];
    #pragma unroll
    for(int j=0;j<32;j++) s = fmaf(h0[j], fc2W[j*26+k], s);
    h[(size_t)n*32+k] = fmaxf(s, 0.f);
  }
}

// ---------------- fused GCN conv kernel ----------------
// One 32-lane group per dst node; lane = feature. Aggregate F_IN features via
// CSR gather, then matmul to F_OUT via width-32 shuffles, bias+ReLU.
// conv1 adds the precomputed aggx/aggones contributions (x3/t3 columns folded
// into summed weight rows). conv3 fuses the fc3->relu->fc4 output head.
template<int F_IN,int F_OUT,bool IS_CONV1,bool FUSE_OUT>
__global__ __launch_bounds__(256,4) void k_conv(
    const int* __restrict__ row_ptr, const int2* __restrict__ pack,
    const float* __restrict__ hin, float* __restrict__ hout,
    const float* __restrict__ W, const float* __restrict__ bias,
    const float* __restrict__ aggx, const float* __restrict__ aggones,
    const float* __restrict__ tptr,
    const float* __restrict__ fc3W, const float* __restrict__ fc3b,
    const float* __restrict__ fc4W, const float* __restrict__ fc4b,
    float* __restrict__ outrow, int N)
{
  const int lane = threadIdx.x & 31;
  const int grp  = threadIdx.x >> 5;                 // 8 groups / block
  const int lo   = lane < F_OUT ? lane : F_OUT-1;    // clamp to avoid undef regs

  float wreg[F_IN];
  #pragma unroll
  for(int f=0;f<F_IN;f++) wreg[f] = W[f*F_OUT + lo];
  float bv = bias[lo];
  float wx=0.f, wt=0.f;
  if constexpr(IS_CONV1){
    wx = W[26*F_OUT+lo] + W[27*F_OUT+lo] + W[28*F_OUT+lo];  // x3 rows summed
    wt = W[29*F_OUT+lo] + W[30*F_OUT+lo] + W[31*F_OUT+lo];  // t3 rows summed
  }
  float f3reg[26]; float f3bv=0.f, f4wv=0.f, f4bv=0.f;
  if constexpr(FUSE_OUT){
    #pragma unroll
    for(int f=0;f<26;f++) f3reg[f]=fc3W[f*32+lane];
    f3bv=fc3b[lane]; f4wv=fc4W[lane]; f4bv=fc4b[0];
  }
  float tval = 0.f;
  if constexpr(IS_CONV1) tval = *tptr;

  const int stride = gridDim.x*8;
  for(int node = blockIdx.x*8+grp; node < N; node += stride){
    const int e0=row_ptr[node], e1=row_ptr[node+1];
    float acc=0.f;
    for(int e=e0;e<e1;e++){
      const int2 p = pack[e];                                  // broadcast 8B
      const float nrm = __int_as_float(p.y);
      const float hv = hin[(size_t)((unsigned)p.x)*32u + lane]; // coalesced 128B
      acc = fmaf(hv, nrm, acc);
    }
    // matmul: out[o] = sum_f agg[f] * W[f][o]
    float sum = 0.f;
    #pragma unroll
    for(int f=0;f<F_IN;f++)
      sum = fmaf(__shfl(acc,f,32), wreg[f], sum);
    float val = sum + bv;
    if constexpr(IS_CONV1) val += aggx[node]*wx + tval*aggones[node]*wt;
    val = fmaxf(val, 0.f);
    if(lane < F_OUT) hout[(size_t)node*32 + lane] = val;
    if constexpr(FUSE_OUT){
      // z = relu(h3 @ fc3W + fc3b);  yy = z @ fc4W + fc4b
      float zs=0.f;
      #pragma unroll
      for(int f=0;f<26;f++) zs = fmaf(__shfl(val,f,32), f3reg[f], zs);
      float z = fmaxf(zs + f3bv, 0.f);
      float part = z * f4wv;
      #pragma unroll
      for(int m=16;m>0;m>>=1) part += __shfl_xor(part, m, 32);
      if(lane==0) outrow[node] = part + f4bv;
    }
  }
}

// ---------------- host launcher ----------------
extern "C" void kernel_launch(void* const* d_in, const int* in_sizes, int n_in,
                              void* d_out, int out_size, void* d_ws, size_t ws_size,
                              hipStream_t stream)
{
  const float* x   = (const float*)d_in[0];
  const float* t   = (const float*)d_in[1];
  const float* y   = (const float*)d_in[2];
  const int*   ei  = (const int*)d_in[3];
  const float* fc1W=(const float*)d_in[4]; const float* fc1b=(const float*)d_in[5];
  const float* fc2W=(const float*)d_in[6]; const float* fc2b=(const float*)d_in[7];
  const float* W1=(const float*)d_in[8];  const float* b1=(const float*)d_in[9];
  const float* W2=(const float*)d_in[10]; const float* b2=(const float*)d_in[11];
  const float* W3=(const float*)d_in[12]; const float* b3=(const float*)d_in[13];
  const float* f3W=(const float*)d_in[14]; const float* f3b=(const float*)d_in[15];
  const float* f4W=(const float*)d_in[16]; const float* f4b=(const float*)d_in[17];
  float* out = (float*)d_out;

  const int N = in_sizes[0];
  const int T = in_sizes[1];
  const int E = in_sizes[3]/2;

  char* base = (char*)d_ws;
  size_t off=0;
  auto carve=[&](size_t bytes)->void*{
    void* p = base+off; off += (bytes+255)&~(size_t)255; return p;
  };
  int*   flag   = (int*)carve(4);
  int*   e32    = (int*)carve((size_t)2*E*4);
  int*   counts = (int*)carve((size_t)N*4);
  float* dis    = (float*)carve((size_t)N*4);
  int*   row_ptr= (int*)carve((size_t)(N+1)*4);
  int*   cursor = (int*)carve((size_t)N*4);
  const int NB = CDIV(N,1024);
  int*   bsums  = (int*)carve((size_t)NB*4);
  int*   boffs  = (int*)carve((size_t)NB*4);
  int2*  pack   = (int2*)carve((size_t)(E+N)*8);
  float* aggx   = (float*)carve((size_t)N*4);
  float* aggo   = (float*)carve((size_t)N*4);
  float* hA     = (float*)carve((size_t)N*32*4);
  float* h1     = (float*)carve((size_t)N*32*4);
  float* h2     = (float*)carve((size_t)N*32*4);
  float* hB     = (float*)carve((size_t)N*32*4);

  int* src = e32; int* dst = e32 + E;

  hipLaunchKernelGGL(k_flag0,   dim3(1),dim3(1),0,stream, flag);
  hipLaunchKernelGGL(k_detect,  dim3(16),dim3(256),0,stream, ei, E, flag);
  hipLaunchKernelGGL(k_convert, dim3(CDIV(2*E,256)),dim3(256),0,stream, ei, 2*E, flag, e32);
  hipLaunchKernelGGL(k_counts1, dim3(CDIV(N,256)),dim3(256),0,stream, counts, N);
  hipLaunchKernelGGL(k_count,   dim3(CDIV(E,256)),dim3(256),0,stream, dst, E, counts);
  hipLaunchKernelGGL(k_dis,     dim3(CDIV(N,256)),dim3(256),0,stream, counts, dis, N);
  hipLaunchKernelGGL(k_scan1,   dim3(NB),dim3(256),0,stream, counts, N, bsums);
  hipLaunchKernelGGL(k_scan2,   dim3(1),dim3(1),0,stream, bsums, NB, boffs, row_ptr, N);
  hipLaunchKernelGGL(k_scan3,   dim3(NB),dim3(256),0,stream, counts, N, boffs, row_ptr, cursor);
  hipLaunchKernelGGL(k_fill,    dim3(CDIV(E+N,256)),dim3(256),0,stream, src, dst, E, N, dis, cursor, pack);
  hipLaunchKernelGGL(k_aggx,    dim3(CDIV(N,256)),dim3(256),0,stream, row_ptr, pack, x, aggx, aggo, N);
  hipLaunchKernelGGL(k_init,    dim3(CDIV(N,256)),dim3(256),0,stream, y, out, fc1W, fc1b, fc2W, fc2b, hA, N);

  const int G = 2048;
  float* hcur = hA; float* hnxt = hB;
  for(int i=0;i<T-1;i++){
    hipLaunchKernelGGL((k_conv<26,32,true,false>), dim3(G),dim3(256),0,stream,
        row_ptr, pack, hcur, h1, W1, b1, aggx, aggo, t+1+i,
        (const float*)nullptr,(const float*)nullptr,(const float*)nullptr,(const float*)nullptr,
        (float*)nullptr, N);
    hipLaunchKernelGGL((k_conv<32,32,false,false>), dim3(G),dim3(256),0,stream,
        row_ptr, pack, h1, h2, W2, b2,
        (const float*)nullptr,(const float*)nullptr,(const float*)nullptr,
        (const float*)nullptr,(const float*)nullptr,(const float*)nullptr,(const float*)nullptr,
        (float*)nullptr, N);
    hipLaunchKernelGGL((k_conv<32,26,false,true>), dim3(G),dim3(256),0,stream,
        row_ptr, pack, h2, hnxt, W3, b3,
        (const float*)nullptr,(const float*)nullptr,(const float*)nullptr,
        f3W, f3b, f4W, f4b, out+(size_t)(i+1)*N, N);
    float* tmp=hcur; hcur=hnxt; hnxt=tmp;
  }
}

// Round 2
// 8808.435 us; speedup vs baseline: 2.2886x; 2.2886x over previous
//
#include <hip/hip_runtime.h>
#include <hip/hip_bf16.h>
#include <stdint.h>

#define CDIV(a,b) (((a)+(b)-1)/(b))

// ---------------- preprocessing kernels ----------------

__global__ void k_flag0(int* flag){ *flag = 0; }

// Detect int32 vs int64 edge_index: view buffer as int32; for int64 data the
// odd positions (high words, values < 2^31) are all zero. For int32 data they
// are random node ids (nonzero w.h.p.). Benign race: all writers store 1.
__global__ void k_detect(const int* __restrict__ ei, int E, int* __restrict__ flag){
  int t = blockIdx.x*blockDim.x + threadIdx.x;
  if(t < 4096 && t < E){
    if(ei[2*t+1] != 0) *flag = 1;
  }
}

// e32[0..E) = src, e32[E..2E) = dst
__global__ void k_convert(const int* __restrict__ ei, int E2, const int* __restrict__ flag,
                          int* __restrict__ out){
  int e = blockIdx.x*blockDim.x + threadIdx.x;
  if(e < E2){
    out[e] = (*flag) ? ei[e] : ei[2*e];   // int64: take low word
  }
}

__global__ void k_counts1(int* __restrict__ counts, int N){
  int i = blockIdx.x*blockDim.x+threadIdx.x;
  if(i<N) counts[i]=1;   // self-loop
}

__global__ void k_count(const int* __restrict__ dst, int E, int* __restrict__ counts){
  int e = blockIdx.x*blockDim.x+threadIdx.x;
  if(e<E) atomicAdd(&counts[dst[e]], 1);
}

__global__ void k_dis(const int* __restrict__ counts, float* __restrict__ dis, int N){
  int i=blockIdx.x*blockDim.x+threadIdx.x;
  if(i<N) dis[i] = rsqrtf((float)counts[i]);
}

// ---- 3-pass exclusive scan (1024 elems / block) ----
__global__ void k_scan1(const int* __restrict__ counts, int N, int* __restrict__ bsums){
  __shared__ int lds[256];
  const int t=threadIdx.x, b=blockIdx.x;
  int basei = b*1024 + t*4;
  int s=0;
  #pragma unroll
  for(int j=0;j<4;j++){ int i=basei+j; if(i<N) s+=counts[i]; }
  lds[t]=s; __syncthreads();
  for(int o=128;o>0;o>>=1){ if(t<o) lds[t]+=lds[t+o]; __syncthreads(); }
  if(t==0) bsums[b]=lds[0];
}

__global__ void k_scan2(const int* __restrict__ bsums, int NB, int* __restrict__ boffs,
                        int* __restrict__ row_ptr, int N){
  int acc=0;
  for(int b=0;b<NB;b++){ boffs[b]=acc; acc+=bsums[b]; }
  row_ptr[N]=acc;
}

__global__ void k_scan3(const int* __restrict__ counts, int N, const int* __restrict__ boffs,
                        int* __restrict__ row_ptr, int* __restrict__ cursor){
  __shared__ int lds[256];
  const int t=threadIdx.x, b=blockIdx.x;
  int basei = b*1024 + t*4;
  int v[4]; int s=0;
  #pragma unroll
  for(int j=0;j<4;j++){ int i=basei+j; v[j]=(i<N)?counts[i]:0; s+=v[j]; }
  lds[t]=s; __syncthreads();
  for(int o=1;o<256;o<<=1){
    int yv = (t>=o)? lds[t-o] : 0;
    __syncthreads();
    lds[t] += yv;
    __syncthreads();
  }
  int run = boffs[b] + lds[t] - s;   // exclusive prefix for this thread
  #pragma unroll
  for(int j=0;j<4;j++){
    int i=basei+j;
    if(i<N){ row_ptr[i]=run; cursor[i]=run; run+=v[j]; }
  }
}

// CSR fill: (src, norm) pairs grouped by dst. Self-loops appended as edges E..E+N.
__global__ void k_fill(const int* __restrict__ src, const int* __restrict__ dst, int E, int N,
                       const float* __restrict__ dis, int* __restrict__ cursor,
                       int2* __restrict__ pack){
  int e = blockIdx.x*blockDim.x+threadIdx.x;
  if(e < E){
    int s=src[e], d=dst[e];
    int pos=atomicAdd(&cursor[d],1);
    pack[pos]=make_int2(s, __float_as_int(dis[s]*dis[d]));
  } else if(e < E+N){
    int i=e-E;
    int pos=atomicAdd(&cursor[i],1);
    float di=dis[i];
    pack[pos]=make_int2(i, __float_as_int(di*di));
  }
}

// Precompute time-invariant aggregates: aggones[d]=sum norm, aggx[d]=sum norm*x[src]
__global__ void k_aggx(const int* __restrict__ row_ptr, const int2* __restrict__ pack,
                       const float* __restrict__ x, float* __restrict__ aggx,
                       float* __restrict__ aggones, int N){
  int n = blockIdx.x*blockDim.x+threadIdx.x;
  if(n>=N) return;
  float sa=0.f, sx=0.f;
  int e1 = row_ptr[n+1];
  for(int e=row_ptr[n]; e<e1; e++){
    int2 p = pack[e];
    float nrm = __int_as_float(p.y);
    sa += nrm;
    sx = fmaf(nrm, x[p.x], sx);
  }
  aggones[n]=sa; aggx[n]=sx;
}

// h = relu(relu(y0 @ fc1W + fc1b) @ fc2W + fc2b), stored stride-32 (26 used).
// Also copies y0 to output row 0.
__global__ void k_init(const float* __restrict__ y0, float* __restrict__ out0,
                       const float* __restrict__ fc1W, const float* __restrict__ fc1b,
                       const float* __restrict__ fc2W, const float* __restrict__ fc2b,
                       float* __restrict__ h, int N){
  int n = blockIdx.x*blockDim.x+threadIdx.x;
  if(n>=N) return;
  float v = y0[n];
  out0[n] = v;
  float h0[32];
  #pragma unroll
  for(int j=0;j<32;j++) h0[j] = fmaxf(fmaf(v, fc1W[j], fc1b[j]), 0.f);
  for(int k=0;k<26;k++){
    float s = fc2b[k];
    #pragma unroll
    for(int j=0;j<32;j++) s = fmaf(h0[j], fc2W[j*26+k], s);
    h[(size_t)n*32+k] = fmaxf(s, 0.f);
  }
}

// ---------------- fused GCN conv kernel ----------------
// One 32-lane group per dst node; lane = feature. Aggregate F_IN features via
// CSR gather (edge loop unrolled x8 for memory-level parallelism; tail handled
// by index-clamp + zero norm so ALL gathers stay batched), then matmul to
// F_OUT via width-32 shuffles, bias+ReLU. conv1 adds precomputed aggx/aggones
// contributions; conv3 fuses the fc3->relu->fc4 output head.
template<int F_IN,int F_OUT,bool IS_CONV1,bool FUSE_OUT>
__global__ __launch_bounds__(256,4) void k_conv(
    const int* __restrict__ row_ptr, const int2* __restrict__ pack,
    const float* __restrict__ hin, float* __restrict__ hout,
    const float* __restrict__ W, const float* __restrict__ bias,
    const float* __restrict__ aggx, const float* __restrict__ aggones,
    const float* __restrict__ tptr,
    const float* __restrict__ fc3W, const float* __restrict__ fc3b,
    const float* __restrict__ fc4W, const float* __restrict__ fc4b,
    float* __restrict__ outrow, int N)
{
  const int lane = threadIdx.x & 31;
  const int grp  = threadIdx.x >> 5;                 // 8 groups / block
  const int lo   = lane < F_OUT ? lane : F_OUT-1;    // clamp to avoid undef regs

  float wreg[F_IN];
  #pragma unroll
  for(int f=0;f<F_IN;f++) wreg[f] = W[f*F_OUT + lo];
  float bv = bias[lo];
  float wx=0.f, wt=0.f;
  if constexpr(IS_CONV1){
    wx = W[26*F_OUT+lo] + W[27*F_OUT+lo] + W[28*F_OUT+lo];  // x3 rows summed
    wt = W[29*F_OUT+lo] + W[30*F_OUT+lo] + W[31*F_OUT+lo];  // t3 rows summed
  }
  float f3reg[26]; float f3bv=0.f, f4wv=0.f, f4bv=0.f;
  if constexpr(FUSE_OUT){
    #pragma unroll
    for(int f=0;f<26;f++) f3reg[f]=fc3W[f*32+lane];
    f3bv=fc3b[lane]; f4wv=fc4W[lane]; f4bv=fc4b[0];
  }
  float tval = 0.f;
  if constexpr(IS_CONV1) tval = *tptr;

  const int stride = gridDim.x*8;
  for(int node = blockIdx.x*8+grp; node < N; node += stride){
    const int e0=row_ptr[node], e1=row_ptr[node+1];
    float acc=0.f;
    // Unroll-by-8 edge loop: 8 independent pack loads, then 8 independent
    // gathers in flight per batch. Tail edges clamp to e0 with norm=0 so the
    // final partial batch still issues all loads in parallel (no serial tail).
    for(int eb=e0; eb<e1; eb+=8){
      int2 p[8];
      #pragma unroll
      for(int j=0;j<8;j++){
        int idx = eb+j;
        p[j] = pack[idx < e1 ? idx : e0];
      }
      float hv[8];
      #pragma unroll
      for(int j=0;j<8;j++)
        hv[j] = hin[(size_t)((unsigned)p[j].x)*32u + lane];
      #pragma unroll
      for(int j=0;j<8;j++){
        float nrm = (eb+j < e1) ? __int_as_float(p[j].y) : 0.f;
        acc = fmaf(hv[j], nrm, acc);
      }
    }
    // matmul: out[o] = sum_f agg[f] * W[f][o]
    float sum = 0.f;
    #pragma unroll
    for(int f=0;f<F_IN;f++)
      sum = fmaf(__shfl(acc,f,32), wreg[f], sum);
    float val = sum + bv;
    if constexpr(IS_CONV1) val += aggx[node]*wx + tval*aggones[node]*wt;
    val = fmaxf(val, 0.f);
    if(lane < F_OUT) hout[(size_t)node*32 + lane] = val;
    if constexpr(FUSE_OUT){
      // z = relu(h3 @ fc3W + fc3b);  yy = z @ fc4W + fc4b
      float zs=0.f;
      #pragma unroll
      for(int f=0;f<26;f++) zs = fmaf(__shfl(val,f,32), f3reg[f], zs);
      float z = fmaxf(zs + f3bv, 0.f);
      float part = z * f4wv;
      #pragma unroll
      for(int m=16;m>0;m>>=1) part += __shfl_xor(part, m, 32);
      if(lane==0) outrow[node] = part + f4bv;
    }
  }
}

// ---------------- host launcher ----------------
extern "C" void kernel_launch(void* const* d_in, const int* in_sizes, int n_in,
                              void* d_out, int out_size, void* d_ws, size_t ws_size,
                              hipStream_t stream)
{
  const float* x   = (const float*)d_in[0];
  const float* t   = (const float*)d_in[1];
  const float* y   = (const float*)d_in[2];
  const int*   ei  = (const int*)d_in[3];
  const float* fc1W=(const float*)d_in[4]; const float* fc1b=(const float*)d_in[5];
  const float* fc2W=(const float*)d_in[6]; const float* fc2b=(const float*)d_in[7];
  const float* W1=(const float*)d_in[8];  const float* b1=(const float*)d_in[9];
  const float* W2=(const float*)d_in[10]; const float* b2=(const float*)d_in[11];
  const float* W3=(const float*)d_in[12]; const float* b3=(const float*)d_in[13];
  const float* f3W=(const float*)d_in[14]; const float* f3b=(const float*)d_in[15];
  const float* f4W=(const float*)d_in[16]; const float* f4b=(const float*)d_in[17];
  float* out = (float*)d_out;

  const int N = in_sizes[0];
  const int T = in_sizes[1];
  const int E = in_sizes[3]/2;

  char* base = (char*)d_ws;
  size_t off=0;
  auto carve=[&](size_t bytes)->void*{
    void* p = base+off; off += (bytes+255)&~(size_t)255; return p;
  };
  int*   flag   = (int*)carve(4);
  int*   e32    = (int*)carve((size_t)2*E*4);
  int*   counts = (int*)carve((size_t)N*4);
  float* dis    = (float*)carve((size_t)N*4);
  int*   row_ptr= (int*)carve((size_t)(N+1)*4);
  int*   cursor = (int*)carve((size_t)N*4);
  const int NB = CDIV(N,1024);
  int*   bsums  = (int*)carve((size_t)NB*4);
  int*   boffs  = (int*)carve((size_t)NB*4);
  int2*  pack   = (int2*)carve((size_t)(E+N)*8);
  float* aggx   = (float*)carve((size_t)N*4);
  float* aggo   = (float*)carve((size_t)N*4);
  float* hA     = (float*)carve((size_t)N*32*4);
  float* h1     = (float*)carve((size_t)N*32*4);
  float* h2     = (float*)carve((size_t)N*32*4);
  float* hB     = (float*)carve((size_t)N*32*4);

  int* src = e32; int* dst = e32 + E;

  hipLaunchKernelGGL(k_flag0,   dim3(1),dim3(1),0,stream, flag);
  hipLaunchKernelGGL(k_detect,  dim3(16),dim3(256),0,stream, ei, E, flag);
  hipLaunchKernelGGL(k_convert, dim3(CDIV(2*E,256)),dim3(256),0,stream, ei, 2*E, flag, e32);
  hipLaunchKernelGGL(k_counts1, dim3(CDIV(N,256)),dim3(256),0,stream, counts, N);
  hipLaunchKernelGGL(k_count,   dim3(CDIV(E,256)),dim3(256),0,stream, dst, E, counts);
  hipLaunchKernelGGL(k_dis,     dim3(CDIV(N,256)),dim3(256),0,stream, counts, dis, N);
  hipLaunchKernelGGL(k_scan1,   dim3(NB),dim3(256),0,stream, counts, N, bsums);
  hipLaunchKernelGGL(k_scan2,   dim3(1),dim3(1),0,stream, bsums, NB, boffs, row_ptr, N);
  hipLaunchKernelGGL(k_scan3,   dim3(NB),dim3(256),0,stream, counts, N, boffs, row_ptr, cursor);
  hipLaunchKernelGGL(k_fill,    dim3(CDIV(E+N,256)),dim3(256),0,stream, src, dst, E, N, dis, cursor, pack);
  hipLaunchKernelGGL(k_aggx,    dim3(CDIV(N,256)),dim3(256),0,stream, row_ptr, pack, x, aggx, aggo, N);
  hipLaunchKernelGGL(k_init,    dim3(CDIV(N,256)),dim3(256),0,stream, y, out, fc1W, fc1b, fc2W, fc2b, hA, N);

  const int G = 2048;
  float* hcur = hA; float* hnxt = hB;
  for(int i=0;i<T-1;i++){
    hipLaunchKernelGGL((k_conv<26,32,true,false>), dim3(G),dim3(256),0,stream,
        row_ptr, pack, hcur, h1, W1, b1, aggx, aggo, t+1+i,
        (const float*)nullptr,(const float*)nullptr,(const float*)nullptr,(const float*)nullptr,
        (float*)nullptr, N);
    hipLaunchKernelGGL((k_conv<32,32,false,false>), dim3(G),dim3(256),0,stream,
        row_ptr, pack, h1, h2, W2, b2,
        (const float*)nullptr,(const float*)nullptr,(const float*)nullptr,
        (const float*)nullptr,(const float*)nullptr,(const float*)nullptr,(const float*)nullptr,
        (float*)nullptr, N);
    hipLaunchKernelGGL((k_conv<32,26,false,true>), dim3(G),dim3(256),0,stream,
        row_ptr, pack, h2, hnxt, W3, b3,
        (const float*)nullptr,(const float*)nullptr,(const float*)nullptr,
        f3W, f3b, f4W, f4b, out+(size_t)(i+1)*N, N);
    float* tmp=hcur; hcur=hnxt; hnxt=tmp;
  }
}